// Round 10
// baseline (1012.634 us; speedup 1.0000x reference)
//
#include <hip/hip_runtime.h>
#include <hip/hip_bf16.h>

#define BATCH 16
#define NPTS  4096
#define NSAMP 1024   // S = N * 0.25
#define KNB   32     // nsample
#define DFEAT 64

#define THREADS  256
#define FPS_PPT  (NPTS / THREADS)   // 16 points per thread
#define NWV      (THREADS / 64)     // 4 waves per block
#define NWBLK    480                // worker blocks (2 per CU alongside FPS)
#define NWAVES   (NWBLK * NWV)      // 1920 worker waves
#define NTASK    (BATCH * NSAMP)    // 16384 (b, sq) tasks
#define TAG_BASE 0xC0FFEE00u

// LDS layout (union of FPS / worker views), 61568 bytes -> 2 blocks/CU.
#define SMEM_BYTES 61568
#define FPS_SXY_OFF 0          // float2[4096]  32 KB
#define FPS_SZ_OFF  32768      // float [4096]  16 KB
#define FPS_STX_OFF 49152      // float [1024]   4 KB
#define FPS_STY_OFF 53248
#define FPS_STZ_OFF 57344
#define FPS_PW_OFF  61440      // u64 [2][4]     64 B (16-aligned)
#define WRK_XLS_OFF 0          // float[4][32][64] 32 KB
#define WRK_H1S_OFF 32768      // float[4][64]   1 KB
#define WRK_GL_OFF  33792      // int[4][32]     512 B

// ---------------------------------------------------------------------------
// DPP wave64 max-reduce round on packed u64 key (key-only).
// Key = (f32_bits(value) << 32) | ~idx : max key == max value, ties -> min idx.
// ---------------------------------------------------------------------------
template <int CTRL, int RMASK>
__device__ __forceinline__ void dpp_round(unsigned long long& key) {
    const int klo = (int)(unsigned)key;
    const int khi = (int)(unsigned)(key >> 32);
    const int tlo = __builtin_amdgcn_update_dpp(klo, klo, CTRL, RMASK, 0xF, false);
    const int thi = __builtin_amdgcn_update_dpp(khi, khi, CTRL, RMASK, 0xF, false);
    const unsigned long long tk =
        ((unsigned long long)(unsigned)thi << 32) | (unsigned)tlo;
    if (tk > key) key = tk;
}

__device__ __forceinline__ void pub_store(unsigned long long* p, unsigned long long v) {
    __hip_atomic_store(p, v, __ATOMIC_RELAXED, __HIP_MEMORY_SCOPE_AGENT);
}
__device__ __forceinline__ unsigned long long pub_load(const unsigned long long* p) {
    return __hip_atomic_load(p, __ATOMIC_RELAXED, __HIP_MEMORY_SCOPE_AGENT);
}

// Barrier waiting only on LDS ops (publish stores stay in flight).
__device__ __forceinline__ void barrier_lds_only() {
    asm volatile("s_waitcnt lgkmcnt(0)" ::: "memory");
    __builtin_amdgcn_s_barrier();
}

// ---------------------------------------------------------------------------
// Fused kernel, 256 threads/block, 496 blocks (all co-resident, <=2/CU).
// Blocks 0..15: FPS (one batch each), publishing each centroid as 3
// self-tagged u64 words. Blocks 16..495: workers (4 waves each) — poll
// centroid, ball query + gather + MLP + maxpool per (b, sq) task.
// ---------------------------------------------------------------------------
__global__ __launch_bounds__(THREADS) void fused_kernel(
    const float* __restrict__ xyz, const float* __restrict__ features,
    const float* __restrict__ W1, const float* __restrict__ b1,
    const float* __restrict__ W2, const float* __restrict__ b2,
    float* __restrict__ out_xyz, float* __restrict__ out_pts,
    unsigned long long* __restrict__ pub) {

    __shared__ alignas(16) unsigned char smem[SMEM_BYTES];
    const int bid  = blockIdx.x;
    const int tid  = threadIdx.x;
    const int lane = tid & 63;
    const int wid  = tid >> 6;

    if (bid < BATCH) {
        // =================== FPS (R6-proven 256-thread math) ===============
        float2* sxy = (float2*)(smem + FPS_SXY_OFF);
        float*  szl = (float*)(smem + FPS_SZ_OFF);
        float*  stX = (float*)(smem + FPS_STX_OFF);
        float*  stY = (float*)(smem + FPS_STY_OFF);
        float*  stZ = (float*)(smem + FPS_STZ_OFF);
        unsigned long long* pw = (unsigned long long*)(smem + FPS_PW_OFF);

        float px[FPS_PPT], py[FPS_PPT], pz[FPS_PPT], md[FPS_PPT];
        const float* base = xyz + (size_t)bid * NPTS * 3;
#pragma unroll
        for (int j = 0; j < FPS_PPT; j++) {
            const int i = j * THREADS + tid;
            const float x = base[i * 3 + 0];
            const float y = base[i * 3 + 1];
            const float z = base[i * 3 + 2];
            sxy[i] = make_float2(x, y);
            szl[i] = z;
            px[j] = x; py[j] = y; pz[j] = z;
            md[j] = 1e10f;
        }

        float cx = base[0], cy = base[1], cz = base[2];
        unsigned long long* pb = pub + (size_t)bid * NSAMP * 3;
        if (tid == 0) {
            stX[0] = cx; stY[0] = cy; stZ[0] = cz;
            pub_store(&pb[0], ((unsigned long long)__float_as_uint(cx) << 32) | (TAG_BASE + 0));
            pub_store(&pb[1], ((unsigned long long)__float_as_uint(cy) << 32) | (TAG_BASE + 0));
            pub_store(&pb[2], ((unsigned long long)__float_as_uint(cz) << 32) | (TAG_BASE + 0));
        }
        __syncthreads();

        for (int s = 1; s < NSAMP; s++) {
            float best = -1.0f;
            int   bj   = 0;
#pragma unroll
            for (int j = 0; j < FPS_PPT; j++) {
                const float dx = px[j] - cx;
                const float dy = py[j] - cy;
                const float dz = pz[j] - cz;
                // match reference rounding: no fma contraction
                const float d = __fadd_rn(__fadd_rn(__fmul_rn(dx, dx), __fmul_rn(dy, dy)),
                                          __fmul_rn(dz, dz));
                const float m = fminf(md[j], d);
                md[j] = m;
                if (m > best) { best = m; bj = j; }   // strict >: lowest j wins
            }
            const int bi = (bj << 8) | tid;           // j*256 + tid (disjoint bits)
            unsigned long long key =
                ((unsigned long long)__float_as_uint(best) << 32) | (unsigned)(~bi);
            dpp_round<0x111, 0xF>(key);  // row_shr:1
            dpp_round<0x112, 0xF>(key);  // row_shr:2
            dpp_round<0x114, 0xF>(key);  // row_shr:4
            dpp_round<0x118, 0xF>(key);  // row_shr:8
            dpp_round<0x142, 0xA>(key);  // row_bcast:15
            dpp_round<0x143, 0xC>(key);  // row_bcast:31 -> lane63 = wave max

            const int par = s & 1;
            if (lane == 63) pw[par * NWV + wid] = key;
            barrier_lds_only();
            const ulong2 p01 = *(const ulong2*)&pw[par * NWV + 0];
            const ulong2 p23 = *(const ulong2*)&pw[par * NWV + 2];
            unsigned long long bk = p01.x;
            if (p01.y > bk) bk = p01.y;
            if (p23.x > bk) bk = p23.x;
            if (p23.y > bk) bk = p23.y;
            const int bix = (int)(~(unsigned)bk);

            // broadcast lookup of next centroid (b64 + b32, issued in parallel)
            const float2 cxy = sxy[bix];
            const float  cz2 = szl[bix];
            cx = cxy.x; cy = cxy.y; cz = cz2;
            if (tid == 0) {
                stX[s] = cx; stY[s] = cy; stZ[s] = cz;
                pub_store(&pb[3 * s + 0], ((unsigned long long)__float_as_uint(cx) << 32) | (TAG_BASE + s));
                pub_store(&pb[3 * s + 1], ((unsigned long long)__float_as_uint(cy) << 32) | (TAG_BASE + s));
                pub_store(&pb[3 * s + 2], ((unsigned long long)__float_as_uint(cz) << 32) | (TAG_BASE + s));
            }
        }

        __syncthreads();
        float* ob = out_xyz + (size_t)bid * 3 * NSAMP;
        for (int i = tid; i < NSAMP; i += THREADS) {
            ob[0 * NSAMP + i] = stX[i];
            ob[1 * NSAMP + i] = stY[i];
            ob[2 * NSAMP + i] = stZ[i];
        }
    } else {
        // ========================== WORKER (4 waves) =======================
        float (*xls)[KNB][DFEAT] = (float (*)[KNB][DFEAT])(smem + WRK_XLS_OFF);
        float (*h1s)[DFEAT]      = (float (*)[DFEAT])(smem + WRK_H1S_OFF);
        int   (*gl)[KNB]         = (int (*)[KNB])(smem + WRK_GL_OFF);

        // weights -> registers (once per wave)
        float w1r[64], w2ra[64], w2rb[64];
        {
            const float4* W1v = (const float4*)(W1 + (size_t)lane * 64);
            const float4* W2a = (const float4*)(W2 + (size_t)lane * 64);
            const float4* W2b = (const float4*)(W2 + (size_t)(lane + 64) * 64);
#pragma unroll
            for (int i = 0; i < 16; i++) {
                float4 v = W1v[i];
                w1r[4 * i] = v.x; w1r[4 * i + 1] = v.y; w1r[4 * i + 2] = v.z; w1r[4 * i + 3] = v.w;
                v = W2a[i];
                w2ra[4 * i] = v.x; w2ra[4 * i + 1] = v.y; w2ra[4 * i + 2] = v.z; w2ra[4 * i + 3] = v.w;
                v = W2b[i];
                w2rb[4 * i] = v.x; w2rb[4 * i + 1] = v.y; w2rb[4 * i + 2] = v.z; w2rb[4 * i + 3] = v.w;
            }
        }
        const float b1r  = b1[lane];
        const float b2ra = b2[lane];
        const float b2rb = b2[lane + 64];

        const int gwave = (bid - BATCH) * NWV + wid;
        for (int t = gwave; t < NTASK; t += NWAVES) {
            const int sq = t >> 4;    // sq-major: waves sweep s together
            const int b  = t & 15;

            // ---- poll centroid (3 self-tagged words; no fences needed) ----
            const unsigned long long* pp = pub + ((size_t)b * NSAMP + sq) * 3;
            const unsigned exp_tag = TAG_BASE + sq;
            unsigned long long w0, w1, w2;
            for (;;) {
                w0 = pub_load(&pp[0]);
                w1 = pub_load(&pp[1]);
                w2 = pub_load(&pp[2]);
                if ((unsigned)w0 == exp_tag && (unsigned)w1 == exp_tag &&
                    (unsigned)w2 == exp_tag) break;
                __builtin_amdgcn_s_sleep(2);
            }
            const float cx = __uint_as_float((unsigned)(w0 >> 32));
            const float cy = __uint_as_float((unsigned)(w1 >> 32));
            const float cz = __uint_as_float((unsigned)(w2 >> 32));

            // ---- ball query into wave-local LDS slice ----
            const float* base = xyz + (size_t)b * NPTS * 3;
            const float r2 = 0.04f;
            int cnt = 0;
            int firstCand = 0x7fffffff;
            for (int bp = 0; bp < NPTS && cnt < KNB; bp += 64) {
                const int p = bp + lane;
                const float dx = base[p * 3 + 0] - cx;
                const float dy = base[p * 3 + 1] - cy;
                const float dz = base[p * 3 + 2] - cz;
                const float d = __fadd_rn(__fadd_rn(__fmul_rn(dx, dx), __fmul_rn(dy, dy)),
                                          __fmul_rn(dz, dz));
                const bool ok = !(d > r2);
                const unsigned long long m = __ballot(ok);
                const int rank = cnt + (int)__popcll(m & ((1ull << lane) - 1ull));
                if (ok && rank < KNB) gl[wid][rank] = p;
                if (ok && rank == 0) firstCand = p;
                cnt += (int)__popcll(m);
            }
            const int found = cnt < KNB ? cnt : KNB;
            if (found < KNB) {
#pragma unroll
                for (int off = 32; off > 0; off >>= 1) {
                    const int o = __shfl_xor(firstCand, off);
                    firstCand = o < firstCand ? o : firstCand;
                }
                for (int r = found + lane; r < KNB; r += 64) gl[wid][r] = firstCand;
            }
            int gi = 0;
            if (lane < KNB) gi = gl[wid][lane];

            // ---- gather 32 neighbor feature rows into LDS ----
            const float* fb = features + (size_t)b * NPTS * DFEAT;
            for (int k = 0; k < KNB; k++) {
                const int idxk = __shfl(gi, k);
                xls[wid][k][lane] = fb[(size_t)idxk * DFEAT + lane];
            }

            // ---- MLP + maxpool ----
            float m0 = 0.0f, m1 = 0.0f;
            for (int k = 0; k < KNB; k++) {
                float acc = b1r;
                const float4* xk = (const float4*)xls[wid][k];
#pragma unroll
                for (int i = 0; i < 16; i++) {
                    const float4 v = xk[i];
                    acc = fmaf(v.x, w1r[4 * i], acc);
                    acc = fmaf(v.y, w1r[4 * i + 1], acc);
                    acc = fmaf(v.z, w1r[4 * i + 2], acc);
                    acc = fmaf(v.w, w1r[4 * i + 3], acc);
                }
                h1s[wid][lane] = fmaxf(acc, 0.0f);
                float a0 = b2ra, a1 = b2rb;
                const float4* hv4 = (const float4*)h1s[wid];
#pragma unroll
                for (int i = 0; i < 16; i++) {
                    const float4 v = hv4[i];
                    a0 = fmaf(v.x, w2ra[4 * i], a0);
                    a0 = fmaf(v.y, w2ra[4 * i + 1], a0);
                    a0 = fmaf(v.z, w2ra[4 * i + 2], a0);
                    a0 = fmaf(v.w, w2ra[4 * i + 3], a0);
                    a1 = fmaf(v.x, w2rb[4 * i], a1);
                    a1 = fmaf(v.y, w2rb[4 * i + 1], a1);
                    a1 = fmaf(v.z, w2rb[4 * i + 2], a1);
                    a1 = fmaf(v.w, w2rb[4 * i + 3], a1);
                }
                m0 = fmaxf(m0, fmaxf(a0, 0.0f));
                m1 = fmaxf(m1, fmaxf(a1, 0.0f));
            }

            out_pts[(size_t)b * 128 * NSAMP + (size_t)lane * NSAMP + sq]        = m0;
            out_pts[(size_t)b * 128 * NSAMP + (size_t)(lane + 64) * NSAMP + sq] = m1;
        }
    }
}

extern "C" void kernel_launch(void* const* d_in, const int* in_sizes, int n_in,
                              void* d_out, int out_size, void* d_ws, size_t ws_size,
                              hipStream_t stream) {
    const float* xyz      = (const float*)d_in[0];
    const float* features = (const float*)d_in[1];
    const float* W1       = (const float*)d_in[2];
    const float* b1       = (const float*)d_in[3];
    const float* W2       = (const float*)d_in[4];
    const float* b2       = (const float*)d_in[5];

    float* out_xyz = (float*)d_out;                                  // [B,3,S]
    float* out_pts = (float*)d_out + (size_t)BATCH * 3 * NSAMP;      // [B,128,S]

    unsigned long long* pub = (unsigned long long*)d_ws;             // [B,S,3]

    fused_kernel<<<BATCH + NWBLK, THREADS, 0, stream>>>(
        xyz, features, W1, b1, W2, b2, out_xyz, out_pts, pub);
}

// Round 11
// 698.716 us; speedup vs baseline: 1.4493x; 1.4493x over previous
//
#include <hip/hip_runtime.h>
#include <hip/hip_bf16.h>

#define BATCH 16
#define NPTS  4096
#define NSAMP 1024   // S = N * 0.25
#define KNB   32     // nsample
#define DFEAT 64

#define THREADS  512
#define NWV      (THREADS / 64)     // 8 waves per block
#define FPS_T    256                // threads doing FPS work (waves 0..3)
#define FPS_PPT  (NPTS / FPS_T)     // 16 points per FPS thread
#define FPS_W    (FPS_T / 64)       // 4 FPS waves
#define NWBLK    240                // worker blocks (1 per CU alongside FPS)
#define NWAVES   (NWBLK * NWV)      // 1920 worker waves
#define NTASK    (BATCH * NSAMP)    // 16384 (b, sq) tasks
#define TAG_BASE 0xC0FFEE00u

// ---------------------------------------------------------------------------
// DPP wave64 max-reduce round on packed u64 key (key-only).
// Key = (f32_bits(value) << 32) | ~idx : max key == max value, ties -> min idx.
// ---------------------------------------------------------------------------
template <int CTRL, int RMASK>
__device__ __forceinline__ void dpp_round(unsigned long long& key) {
    const int klo = (int)(unsigned)key;
    const int khi = (int)(unsigned)(key >> 32);
    const int tlo = __builtin_amdgcn_update_dpp(klo, klo, CTRL, RMASK, 0xF, false);
    const int thi = __builtin_amdgcn_update_dpp(khi, khi, CTRL, RMASK, 0xF, false);
    const unsigned long long tk =
        ((unsigned long long)(unsigned)thi << 32) | (unsigned)tlo;
    if (tk > key) key = tk;
}

__device__ __forceinline__ void pub_store(unsigned long long* p, unsigned long long v) {
    __hip_atomic_store(p, v, __ATOMIC_RELAXED, __HIP_MEMORY_SCOPE_AGENT);
}
__device__ __forceinline__ unsigned long long pub_load(const unsigned long long* p) {
    return __hip_atomic_load(p, __ATOMIC_RELAXED, __HIP_MEMORY_SCOPE_AGENT);
}

// Barrier waiting only on LDS ops (publish stores stay in flight).
__device__ __forceinline__ void barrier_lds_only() {
    asm volatile("s_waitcnt lgkmcnt(0)" ::: "memory");
    __builtin_amdgcn_s_barrier();
}

// ---------------------------------------------------------------------------
// Fused kernel, 512 threads/block, 256 blocks, 1 block/CU.
// Blocks 0..15: FPS — waves 0..3 run the R6-proven 256-thread FPS step
// (16 pts/thread, key-only DPP, 4 partials, b128 coord lookup); waves 4..7
// only execute the matching barrier sequence (idle producers' companions).
// Blocks 16..255: workers (8 waves) — poll centroid, ball query + gather +
// MLP + maxpool per (b, sq) task, sq-major order.
// ---------------------------------------------------------------------------
__global__ __launch_bounds__(THREADS) void fused_kernel(
    const float* __restrict__ xyz, const float* __restrict__ features,
    const float* __restrict__ W1, const float* __restrict__ b1,
    const float* __restrict__ W2, const float* __restrict__ b2,
    float* __restrict__ out_xyz, float* __restrict__ out_pts,
    unsigned long long* __restrict__ pub) {

    __shared__ alignas(16) unsigned char smem[65536 + 12288 + 64];
    const int bid  = blockIdx.x;
    const int tid  = threadIdx.x;
    const int lane = tid & 63;
    const int wid  = tid >> 6;

    if (bid < BATCH) {
        // ============================ FPS =================================
        float4* sc = (float4*)smem;                          // 64 KB coords
        float* stX = (float*)(smem + 65536);                 // 12 KB staging
        float* stY = stX + NSAMP;
        float* stZ = stY + NSAMP;
        unsigned long long* pw = (unsigned long long*)(smem + 65536 + 12288);

        const bool fpsw = (wid < FPS_W);
        float px[FPS_PPT], py[FPS_PPT], pz[FPS_PPT], md[FPS_PPT];
        const float* base = xyz + (size_t)bid * NPTS * 3;
        float cx = 0.0f, cy = 0.0f, cz = 0.0f;
        unsigned long long* pb = pub + (size_t)bid * NSAMP * 3;

        if (fpsw) {
#pragma unroll
            for (int j = 0; j < FPS_PPT; j++) {
                const int i = j * FPS_T + tid;
                const float x = base[i * 3 + 0];
                const float y = base[i * 3 + 1];
                const float z = base[i * 3 + 2];
                sc[i] = make_float4(x, y, z, 0.0f);
                px[j] = x; py[j] = y; pz[j] = z;
                md[j] = 1e10f;
            }
            cx = base[0]; cy = base[1]; cz = base[2];
            if (tid == 0) {
                stX[0] = cx; stY[0] = cy; stZ[0] = cz;
                pub_store(&pb[0], ((unsigned long long)__float_as_uint(cx) << 32) | (TAG_BASE + 0));
                pub_store(&pb[1], ((unsigned long long)__float_as_uint(cy) << 32) | (TAG_BASE + 0));
                pub_store(&pb[2], ((unsigned long long)__float_as_uint(cz) << 32) | (TAG_BASE + 0));
            }
        }
        __syncthreads();

        for (int s = 1; s < NSAMP; s++) {
            if (fpsw) {
                float best = -1.0f;
                int   bj   = 0;
#pragma unroll
                for (int j = 0; j < FPS_PPT; j++) {
                    const float dx = px[j] - cx;
                    const float dy = py[j] - cy;
                    const float dz = pz[j] - cz;
                    // match reference rounding: no fma contraction
                    const float d = __fadd_rn(__fadd_rn(__fmul_rn(dx, dx), __fmul_rn(dy, dy)),
                                              __fmul_rn(dz, dz));
                    const float m = fminf(md[j], d);
                    md[j] = m;
                    if (m > best) { best = m; bj = j; }   // strict >: lowest j wins
                }
                const int bi = (bj << 8) | tid;           // j*256 + tid (disjoint bits)
                unsigned long long key =
                    ((unsigned long long)__float_as_uint(best) << 32) | (unsigned)(~bi);
                dpp_round<0x111, 0xF>(key);  // row_shr:1
                dpp_round<0x112, 0xF>(key);  // row_shr:2
                dpp_round<0x114, 0xF>(key);  // row_shr:4
                dpp_round<0x118, 0xF>(key);  // row_shr:8
                dpp_round<0x142, 0xA>(key);  // row_bcast:15
                dpp_round<0x143, 0xC>(key);  // row_bcast:31 -> lane63 = wave max
                if (lane == 63) pw[(s & 1) * FPS_W + wid] = key;
            }
            barrier_lds_only();
            if (fpsw) {
                const int par = s & 1;
                const ulong2 p01 = *(const ulong2*)&pw[par * FPS_W + 0];
                const ulong2 p23 = *(const ulong2*)&pw[par * FPS_W + 2];
                unsigned long long bk = p01.x;
                if (p01.y > bk) bk = p01.y;
                if (p23.x > bk) bk = p23.x;
                if (p23.y > bk) bk = p23.y;
                const int bix = (int)(~(unsigned)bk);

                const float4 c = sc[bix];   // broadcast ds_read_b128
                cx = c.x; cy = c.y; cz = c.z;
                if (tid == 0) {
                    stX[s] = cx; stY[s] = cy; stZ[s] = cz;
                    pub_store(&pb[3 * s + 0], ((unsigned long long)__float_as_uint(cx) << 32) | (TAG_BASE + s));
                    pub_store(&pb[3 * s + 1], ((unsigned long long)__float_as_uint(cy) << 32) | (TAG_BASE + s));
                    pub_store(&pb[3 * s + 2], ((unsigned long long)__float_as_uint(cz) << 32) | (TAG_BASE + s));
                }
            }
        }

        __syncthreads();
        float* ob = out_xyz + (size_t)bid * 3 * NSAMP;
        for (int i = tid; i < NSAMP; i += THREADS) {
            ob[0 * NSAMP + i] = stX[i];
            ob[1 * NSAMP + i] = stY[i];
            ob[2 * NSAMP + i] = stZ[i];
        }
    } else {
        // ========================== WORKER (8 waves) =======================
        float (*xls)[KNB][DFEAT] = (float (*)[KNB][DFEAT])smem;          // 64 KB
        float (*h1s)[DFEAT]      = (float (*)[DFEAT])(smem + 65536);     // 2 KB
        int   (*gl)[KNB]         = (int (*)[KNB])(smem + 65536 + 8192);  // 1 KB

        // weights -> registers (once per wave)
        float w1r[64], w2ra[64], w2rb[64];
        {
            const float4* W1v = (const float4*)(W1 + (size_t)lane * 64);
            const float4* W2a = (const float4*)(W2 + (size_t)lane * 64);
            const float4* W2b = (const float4*)(W2 + (size_t)(lane + 64) * 64);
#pragma unroll
            for (int i = 0; i < 16; i++) {
                float4 v = W1v[i];
                w1r[4 * i] = v.x; w1r[4 * i + 1] = v.y; w1r[4 * i + 2] = v.z; w1r[4 * i + 3] = v.w;
                v = W2a[i];
                w2ra[4 * i] = v.x; w2ra[4 * i + 1] = v.y; w2ra[4 * i + 2] = v.z; w2ra[4 * i + 3] = v.w;
                v = W2b[i];
                w2rb[4 * i] = v.x; w2rb[4 * i + 1] = v.y; w2rb[4 * i + 2] = v.z; w2rb[4 * i + 3] = v.w;
            }
        }
        const float b1r  = b1[lane];
        const float b2ra = b2[lane];
        const float b2rb = b2[lane + 64];

        const int gwave = (bid - BATCH) * NWV + wid;
        for (int t = gwave; t < NTASK; t += NWAVES) {
            const int sq = t >> 4;    // sq-major: waves sweep s together
            const int b  = t & 15;

            // ---- poll centroid (3 self-tagged words; no fences needed) ----
            const unsigned long long* pp = pub + ((size_t)b * NSAMP + sq) * 3;
            const unsigned exp_tag = TAG_BASE + sq;
            unsigned long long w0, w1, w2;
            for (;;) {
                w0 = pub_load(&pp[0]);
                w1 = pub_load(&pp[1]);
                w2 = pub_load(&pp[2]);
                if ((unsigned)w0 == exp_tag && (unsigned)w1 == exp_tag &&
                    (unsigned)w2 == exp_tag) break;
                __builtin_amdgcn_s_sleep(2);
            }
            const float cx = __uint_as_float((unsigned)(w0 >> 32));
            const float cy = __uint_as_float((unsigned)(w1 >> 32));
            const float cz = __uint_as_float((unsigned)(w2 >> 32));

            // ---- ball query into wave-local LDS slice ----
            const float* base = xyz + (size_t)b * NPTS * 3;
            const float r2 = 0.04f;
            int cnt = 0;
            int firstCand = 0x7fffffff;
            for (int bp = 0; bp < NPTS && cnt < KNB; bp += 64) {
                const int p = bp + lane;
                const float dx = base[p * 3 + 0] - cx;
                const float dy = base[p * 3 + 1] - cy;
                const float dz = base[p * 3 + 2] - cz;
                const float d = __fadd_rn(__fadd_rn(__fmul_rn(dx, dx), __fmul_rn(dy, dy)),
                                          __fmul_rn(dz, dz));
                const bool ok = !(d > r2);
                const unsigned long long m = __ballot(ok);
                const int rank = cnt + (int)__popcll(m & ((1ull << lane) - 1ull));
                if (ok && rank < KNB) gl[wid][rank] = p;
                if (ok && rank == 0) firstCand = p;
                cnt += (int)__popcll(m);
            }
            const int found = cnt < KNB ? cnt : KNB;
            if (found < KNB) {
#pragma unroll
                for (int off = 32; off > 0; off >>= 1) {
                    const int o = __shfl_xor(firstCand, off);
                    firstCand = o < firstCand ? o : firstCand;
                }
                for (int r = found + lane; r < KNB; r += 64) gl[wid][r] = firstCand;
            }
            int gi = 0;
            if (lane < KNB) gi = gl[wid][lane];

            // ---- gather 32 neighbor feature rows into LDS ----
            const float* fb = features + (size_t)b * NPTS * DFEAT;
            for (int k = 0; k < KNB; k++) {
                const int idxk = __shfl(gi, k);
                xls[wid][k][lane] = fb[(size_t)idxk * DFEAT + lane];
            }

            // ---- MLP + maxpool ----
            float m0 = 0.0f, m1 = 0.0f;
            for (int k = 0; k < KNB; k++) {
                float acc = b1r;
                const float4* xk = (const float4*)xls[wid][k];
#pragma unroll
                for (int i = 0; i < 16; i++) {
                    const float4 v = xk[i];
                    acc = fmaf(v.x, w1r[4 * i], acc);
                    acc = fmaf(v.y, w1r[4 * i + 1], acc);
                    acc = fmaf(v.z, w1r[4 * i + 2], acc);
                    acc = fmaf(v.w, w1r[4 * i + 3], acc);
                }
                h1s[wid][lane] = fmaxf(acc, 0.0f);
                float a0 = b2ra, a1 = b2rb;
                const float4* hv4 = (const float4*)h1s[wid];
#pragma unroll
                for (int i = 0; i < 16; i++) {
                    const float4 v = hv4[i];
                    a0 = fmaf(v.x, w2ra[4 * i], a0);
                    a0 = fmaf(v.y, w2ra[4 * i + 1], a0);
                    a0 = fmaf(v.z, w2ra[4 * i + 2], a0);
                    a0 = fmaf(v.w, w2ra[4 * i + 3], a0);
                    a1 = fmaf(v.x, w2rb[4 * i], a1);
                    a1 = fmaf(v.y, w2rb[4 * i + 1], a1);
                    a1 = fmaf(v.z, w2rb[4 * i + 2], a1);
                    a1 = fmaf(v.w, w2rb[4 * i + 3], a1);
                }
                m0 = fmaxf(m0, fmaxf(a0, 0.0f));
                m1 = fmaxf(m1, fmaxf(a1, 0.0f));
            }

            out_pts[(size_t)b * 128 * NSAMP + (size_t)lane * NSAMP + sq]        = m0;
            out_pts[(size_t)b * 128 * NSAMP + (size_t)(lane + 64) * NSAMP + sq] = m1;
        }
    }
}

extern "C" void kernel_launch(void* const* d_in, const int* in_sizes, int n_in,
                              void* d_out, int out_size, void* d_ws, size_t ws_size,
                              hipStream_t stream) {
    const float* xyz      = (const float*)d_in[0];
    const float* features = (const float*)d_in[1];
    const float* W1       = (const float*)d_in[2];
    const float* b1       = (const float*)d_in[3];
    const float* W2       = (const float*)d_in[4];
    const float* b2       = (const float*)d_in[5];

    float* out_xyz = (float*)d_out;                                  // [B,3,S]
    float* out_pts = (float*)d_out + (size_t)BATCH * 3 * NSAMP;      // [B,128,S]

    unsigned long long* pub = (unsigned long long*)d_ws;             // [B,S,3]

    fused_kernel<<<BATCH + NWBLK, THREADS, 0, stream>>>(
        xyz, features, W1, b1, W2, b2, out_xyz, out_pts, pub);
}

// Round 12
// 667.653 us; speedup vs baseline: 1.5167x; 1.0465x over previous
//
#include <hip/hip_runtime.h>
#include <hip/hip_bf16.h>

#define BATCH 16
#define NPTS  4096
#define NSAMP 1024   // S = N * 0.25
#define KNB   32     // nsample
#define DFEAT 64

#define THREADS  512
#define FPS_PPT  (NPTS / THREADS)   // 8 points per thread
#define NWV      (THREADS / 64)     // 8 waves per block
#define NWBLK    240                // worker blocks
#define NWAVES   (NWBLK * NWV)      // 1920 worker waves
#define NTASK    (BATCH * NSAMP)    // 16384 (b, sq) tasks
#define TAG_BASE 0xC0FFEE00u

// ---------------------------------------------------------------------------
// DPP wave64 max-reduce round on packed u64 key (key-only).
// Key = (f32_bits(value) << 32) | ~idx : max key == max value, ties -> min idx.
// ---------------------------------------------------------------------------
template <int CTRL, int RMASK>
__device__ __forceinline__ void dpp_round(unsigned long long& key) {
    const int klo = (int)(unsigned)key;
    const int khi = (int)(unsigned)(key >> 32);
    const int tlo = __builtin_amdgcn_update_dpp(klo, klo, CTRL, RMASK, 0xF, false);
    const int thi = __builtin_amdgcn_update_dpp(khi, khi, CTRL, RMASK, 0xF, false);
    const unsigned long long tk =
        ((unsigned long long)(unsigned)thi << 32) | (unsigned)tlo;
    if (tk > key) key = tk;
}

__device__ __forceinline__ void pub_store(unsigned long long* p, unsigned long long v) {
    __hip_atomic_store(p, v, __ATOMIC_RELAXED, __HIP_MEMORY_SCOPE_AGENT);
}
__device__ __forceinline__ unsigned long long pub_load(const unsigned long long* p) {
    return __hip_atomic_load(p, __ATOMIC_RELAXED, __HIP_MEMORY_SCOPE_AGENT);
}

// Barrier waiting only on LDS ops (publish stores stay in flight).
__device__ __forceinline__ void barrier_lds_only() {
    asm volatile("s_waitcnt lgkmcnt(0)" ::: "memory");
    __builtin_amdgcn_s_barrier();
}

// ---------------------------------------------------------------------------
// Fused kernel, 512 threads/block. Blocks 0..15: FPS (one batch each),
// publishing each centroid as 3 self-tagged u64 words. Blocks 16..255:
// workers (8 waves each). Poll is LANE-0-ONLY (same-address per-lane atomic
// loads are not coalesced -- 64x traffic amplification observed in R9/R11:
// FETCH_SIZE ~29 GB), then wave-broadcast via shfl.
// ---------------------------------------------------------------------------
__global__ __launch_bounds__(THREADS) void fused_kernel(
    const float* __restrict__ xyz, const float* __restrict__ features,
    const float* __restrict__ W1, const float* __restrict__ b1,
    const float* __restrict__ W2, const float* __restrict__ b2,
    float* __restrict__ out_xyz, float* __restrict__ out_pts,
    unsigned long long* __restrict__ pub) {

    __shared__ alignas(16) unsigned char smem[65536 + 12288 + 128];
    const int bid  = blockIdx.x;
    const int tid  = threadIdx.x;
    const int lane = tid & 63;
    const int wid  = tid >> 6;

    if (bid < BATCH) {
        // =================== FPS (R9 form, 8 waves) ========================
        float4* sc = (float4*)smem;                          // 64 KB coords
        float* stX = (float*)(smem + 65536);                 // 12 KB staging
        float* stY = stX + NSAMP;
        float* stZ = stY + NSAMP;
        unsigned long long* pw = (unsigned long long*)(smem + 65536 + 12288);

        float px[FPS_PPT], py[FPS_PPT], pz[FPS_PPT], md[FPS_PPT];
        const float* base = xyz + (size_t)bid * NPTS * 3;
#pragma unroll
        for (int j = 0; j < FPS_PPT; j++) {
            const int i = j * THREADS + tid;
            const float x = base[i * 3 + 0];
            const float y = base[i * 3 + 1];
            const float z = base[i * 3 + 2];
            sc[i] = make_float4(x, y, z, 0.0f);
            px[j] = x; py[j] = y; pz[j] = z;
            md[j] = 1e10f;
        }

        float cx = base[0], cy = base[1], cz = base[2];
        unsigned long long* pb = pub + (size_t)bid * NSAMP * 3;
        if (tid == 0) {
            stX[0] = cx; stY[0] = cy; stZ[0] = cz;
            pub_store(&pb[0], ((unsigned long long)__float_as_uint(cx) << 32) | (TAG_BASE + 0));
            pub_store(&pb[1], ((unsigned long long)__float_as_uint(cy) << 32) | (TAG_BASE + 0));
            pub_store(&pb[2], ((unsigned long long)__float_as_uint(cz) << 32) | (TAG_BASE + 0));
        }
        __syncthreads();

        for (int s = 1; s < NSAMP; s++) {
            float best = -1.0f;
            int   bj   = 0;
#pragma unroll
            for (int j = 0; j < FPS_PPT; j++) {
                const float dx = px[j] - cx;
                const float dy = py[j] - cy;
                const float dz = pz[j] - cz;
                // match reference rounding: no fma contraction
                const float d = __fadd_rn(__fadd_rn(__fmul_rn(dx, dx), __fmul_rn(dy, dy)),
                                          __fmul_rn(dz, dz));
                const float m = fminf(md[j], d);
                md[j] = m;
                if (m > best) { best = m; bj = j; }
            }
            const int bi = (bj << 9) | tid;    // j*512 + tid (disjoint bits)
            unsigned long long key =
                ((unsigned long long)__float_as_uint(best) << 32) | (unsigned)(~bi);
            dpp_round<0x111, 0xF>(key);
            dpp_round<0x112, 0xF>(key);
            dpp_round<0x114, 0xF>(key);
            dpp_round<0x118, 0xF>(key);
            dpp_round<0x142, 0xA>(key);
            dpp_round<0x143, 0xC>(key);

            const int par = s & 1;
            if (lane == 63) pw[par * NWV + wid] = key;
            barrier_lds_only();
            const ulong2 p01 = *(const ulong2*)&pw[par * NWV + 0];
            const ulong2 p23 = *(const ulong2*)&pw[par * NWV + 2];
            const ulong2 p45 = *(const ulong2*)&pw[par * NWV + 4];
            const ulong2 p67 = *(const ulong2*)&pw[par * NWV + 6];
            unsigned long long bk = p01.x;
            if (p01.y > bk) bk = p01.y;
            if (p23.x > bk) bk = p23.x;
            if (p23.y > bk) bk = p23.y;
            if (p45.x > bk) bk = p45.x;
            if (p45.y > bk) bk = p45.y;
            if (p67.x > bk) bk = p67.x;
            if (p67.y > bk) bk = p67.y;
            const int bix = (int)(~(unsigned)bk);

            const float4 c = sc[bix];
            cx = c.x; cy = c.y; cz = c.z;
            if (tid == 0) {
                stX[s] = cx; stY[s] = cy; stZ[s] = cz;
                pub_store(&pb[3 * s + 0], ((unsigned long long)__float_as_uint(cx) << 32) | (TAG_BASE + s));
                pub_store(&pb[3 * s + 1], ((unsigned long long)__float_as_uint(cy) << 32) | (TAG_BASE + s));
                pub_store(&pb[3 * s + 2], ((unsigned long long)__float_as_uint(cz) << 32) | (TAG_BASE + s));
            }
        }

        __syncthreads();
        float* ob = out_xyz + (size_t)bid * 3 * NSAMP;
        for (int i = tid; i < NSAMP; i += THREADS) {
            ob[0 * NSAMP + i] = stX[i];
            ob[1 * NSAMP + i] = stY[i];
            ob[2 * NSAMP + i] = stZ[i];
        }
    } else {
        // ========================== WORKER (8 waves) =======================
        float (*xls)[KNB][DFEAT] = (float (*)[KNB][DFEAT])smem;          // 64 KB
        float (*h1s)[DFEAT]      = (float (*)[DFEAT])(smem + 65536);     // 2 KB
        int   (*gl)[KNB]         = (int (*)[KNB])(smem + 65536 + 2048);  // 1 KB

        // weights -> registers (once per wave)
        float w1r[64], w2ra[64], w2rb[64];
        {
            const float4* W1v = (const float4*)(W1 + (size_t)lane * 64);
            const float4* W2a = (const float4*)(W2 + (size_t)lane * 64);
            const float4* W2b = (const float4*)(W2 + (size_t)(lane + 64) * 64);
#pragma unroll
            for (int i = 0; i < 16; i++) {
                float4 v = W1v[i];
                w1r[4 * i] = v.x; w1r[4 * i + 1] = v.y; w1r[4 * i + 2] = v.z; w1r[4 * i + 3] = v.w;
                v = W2a[i];
                w2ra[4 * i] = v.x; w2ra[4 * i + 1] = v.y; w2ra[4 * i + 2] = v.z; w2ra[4 * i + 3] = v.w;
                v = W2b[i];
                w2rb[4 * i] = v.x; w2rb[4 * i + 1] = v.y; w2rb[4 * i + 2] = v.z; w2rb[4 * i + 3] = v.w;
            }
        }
        const float b1r  = b1[lane];
        const float b2ra = b2[lane];
        const float b2rb = b2[lane + 64];

        const int gwave = (bid - BATCH) * NWV + wid;
        for (int t = gwave; t < NTASK; t += NWAVES) {
            const int sq = t >> 4;    // sq-major: waves sweep s together
            const int b  = t & 15;

            // ---- poll centroid: LANE 0 ONLY, then wave-broadcast ----------
            const unsigned long long* pp = pub + ((size_t)b * NSAMP + sq) * 3;
            const unsigned exp_tag = TAG_BASE + sq;
            float pxf = 0.0f, pyf = 0.0f, pzf = 0.0f;
            if (lane == 0) {
                unsigned long long w0, w1, w2;
                for (;;) {
                    w0 = pub_load(&pp[0]);
                    w1 = pub_load(&pp[1]);
                    w2 = pub_load(&pp[2]);
                    if ((unsigned)w0 == exp_tag && (unsigned)w1 == exp_tag &&
                        (unsigned)w2 == exp_tag) break;
                    __builtin_amdgcn_s_sleep(2);
                }
                pxf = __uint_as_float((unsigned)(w0 >> 32));
                pyf = __uint_as_float((unsigned)(w1 >> 32));
                pzf = __uint_as_float((unsigned)(w2 >> 32));
            }
            const float cx = __shfl(pxf, 0);
            const float cy = __shfl(pyf, 0);
            const float cz = __shfl(pzf, 0);

            // ---- ball query into wave-local LDS slice ----
            const float* base = xyz + (size_t)b * NPTS * 3;
            const float r2 = 0.04f;
            int cnt = 0;
            int firstCand = 0x7fffffff;
            for (int bp = 0; bp < NPTS && cnt < KNB; bp += 64) {
                const int p = bp + lane;
                const float dx = base[p * 3 + 0] - cx;
                const float dy = base[p * 3 + 1] - cy;
                const float dz = base[p * 3 + 2] - cz;
                const float d = __fadd_rn(__fadd_rn(__fmul_rn(dx, dx), __fmul_rn(dy, dy)),
                                          __fmul_rn(dz, dz));
                const bool ok = !(d > r2);
                const unsigned long long m = __ballot(ok);
                const int rank = cnt + (int)__popcll(m & ((1ull << lane) - 1ull));
                if (ok && rank < KNB) gl[wid][rank] = p;
                if (ok && rank == 0) firstCand = p;
                cnt += (int)__popcll(m);
            }
            const int found = cnt < KNB ? cnt : KNB;
            if (found < KNB) {
#pragma unroll
                for (int off = 32; off > 0; off >>= 1) {
                    const int o = __shfl_xor(firstCand, off);
                    firstCand = o < firstCand ? o : firstCand;
                }
                for (int r = found + lane; r < KNB; r += 64) gl[wid][r] = firstCand;
            }
            int gi = 0;
            if (lane < KNB) gi = gl[wid][lane];

            // ---- gather 32 neighbor feature rows into LDS ----
            const float* fb = features + (size_t)b * NPTS * DFEAT;
            for (int k = 0; k < KNB; k++) {
                const int idxk = __shfl(gi, k);
                xls[wid][k][lane] = fb[(size_t)idxk * DFEAT + lane];
            }

            // ---- MLP + maxpool ----
            float m0 = 0.0f, m1 = 0.0f;
            for (int k = 0; k < KNB; k++) {
                float acc = b1r;
                const float4* xk = (const float4*)xls[wid][k];
#pragma unroll
                for (int i = 0; i < 16; i++) {
                    const float4 v = xk[i];
                    acc = fmaf(v.x, w1r[4 * i], acc);
                    acc = fmaf(v.y, w1r[4 * i + 1], acc);
                    acc = fmaf(v.z, w1r[4 * i + 2], acc);
                    acc = fmaf(v.w, w1r[4 * i + 3], acc);
                }
                h1s[wid][lane] = fmaxf(acc, 0.0f);
                float a0 = b2ra, a1 = b2rb;
                const float4* hv4 = (const float4*)h1s[wid];
#pragma unroll
                for (int i = 0; i < 16; i++) {
                    const float4 v = hv4[i];
                    a0 = fmaf(v.x, w2ra[4 * i], a0);
                    a0 = fmaf(v.y, w2ra[4 * i + 1], a0);
                    a0 = fmaf(v.z, w2ra[4 * i + 2], a0);
                    a0 = fmaf(v.w, w2ra[4 * i + 3], a0);
                    a1 = fmaf(v.x, w2rb[4 * i], a1);
                    a1 = fmaf(v.y, w2rb[4 * i + 1], a1);
                    a1 = fmaf(v.z, w2rb[4 * i + 2], a1);
                    a1 = fmaf(v.w, w2rb[4 * i + 3], a1);
                }
                m0 = fmaxf(m0, fmaxf(a0, 0.0f));
                m1 = fmaxf(m1, fmaxf(a1, 0.0f));
            }

            out_pts[(size_t)b * 128 * NSAMP + (size_t)lane * NSAMP + sq]        = m0;
            out_pts[(size_t)b * 128 * NSAMP + (size_t)(lane + 64) * NSAMP + sq] = m1;
        }
    }
}

extern "C" void kernel_launch(void* const* d_in, const int* in_sizes, int n_in,
                              void* d_out, int out_size, void* d_ws, size_t ws_size,
                              hipStream_t stream) {
    const float* xyz      = (const float*)d_in[0];
    const float* features = (const float*)d_in[1];
    const float* W1       = (const float*)d_in[2];
    const float* b1       = (const float*)d_in[3];
    const float* W2       = (const float*)d_in[4];
    const float* b2       = (const float*)d_in[5];

    float* out_xyz = (float*)d_out;                                  // [B,3,S]
    float* out_pts = (float*)d_out + (size_t)BATCH * 3 * NSAMP;      // [B,128,S]

    unsigned long long* pub = (unsigned long long*)d_ws;             // [B,S,3]

    fused_kernel<<<BATCH + NWBLK, THREADS, 0, stream>>>(
        xyz, features, W1, b1, W2, b2, out_xyz, out_pts, pub);
}